// Round 6
// baseline (624.255 us; speedup 1.0000x reference)
//
#include <hip/hip_runtime.h>
#include <cmath>

#define H 128
#define EPS 1e-5f

typedef __attribute__((ext_vector_type(8))) __bf16 bf16x8;
typedef __attribute__((ext_vector_type(4))) float f32x4;
typedef __attribute__((ext_vector_type(2))) float f32x2;
typedef __attribute__((ext_vector_type(4))) unsigned short u16x4;
typedef __attribute__((ext_vector_type(8))) unsigned short u16x8;

__device__ __forceinline__ float gelu_exact(float x) {
    return 0.5f * x * (1.0f + erff(x * 0.70710678118654752f));
}

__device__ __forceinline__ unsigned short f2bfu(float f) {
    __bf16 h = (__bf16)f;   // RNE fptrunc
    return __builtin_bit_cast(unsigned short, h);
}

// ---------------------------------------------------------------------------
// Preprocessing: counting sort of edges by dst -> perm (dst-grouped edge ids),
// offs (group starts). scan writes ONLY offs; the scatter cursor is a
// separately DMA-zeroed cnt2 (no plain-write -> atomic-RMW aliasing).
// ---------------------------------------------------------------------------
__global__ __launch_bounds__(256) void hist_kernel(const int* __restrict__ dst,
                                                   int* __restrict__ cnt, int E)
{
    int i = blockIdx.x * blockDim.x + threadIdx.x;
    const int stride = gridDim.x * blockDim.x;
    for (; i < E; i += stride) atomicAdd(&cnt[dst[i]], 1);
}

__global__ __launch_bounds__(1024) void scan_kernel(const int* __restrict__ cnt,
                                                    int* __restrict__ offs,
                                                    int Nn, int E)
{
    __shared__ int part[1024];
    const int t = threadIdx.x;
    const int CH = (Nn + 1023) / 1024;
    const int base = t * CH;
    int s = 0;
    for (int i = 0; i < CH; ++i) {
        int idx = base + i;
        if (idx < Nn) s += cnt[idx];
    }
    part[t] = s;
    __syncthreads();
    for (int d = 1; d < 1024; d <<= 1) {
        int v = (t >= d) ? part[t - d] : 0;
        __syncthreads();
        part[t] += v;
        __syncthreads();
    }
    int run = (t > 0) ? part[t - 1] : 0;
    for (int i = 0; i < CH; ++i) {
        int idx = base + i;
        if (idx < Nn) {
            offs[idx] = run;
            run += cnt[idx];
        }
    }
    if (t == 0) offs[Nn] = E;
}

__global__ __launch_bounds__(256) void scatter_perm(const int* __restrict__ dst,
                                                    const int* __restrict__ offs,
                                                    int* __restrict__ cur2,
                                                    int* __restrict__ perm, int E)
{
    int i = blockIdx.x * blockDim.x + threadIdx.x;
    const int stride = gridDim.x * blockDim.x;
    for (; i < E; i += stride) {
        int n = dst[i];
        int p = offs[n] + atomicAdd(&cur2[n], 1);
        perm[p] = i;
    }
}

// ---------------------------------------------------------------------------
// Phase A: streaming edge MLP — NO LDS, NO BARRIERS, NATURAL-ORDER writes.
// Swapped-operand MFMA: D[i][j] = sum_k W1[n0+i][k] * posE[e0+j][k].
// B-fragment for lane (lg,lr) = posE[e0+lr][kk*32+lg*8 .. +8]: 8 contiguous
// floats loaded DIRECTLY from global (ea row + x[src] row). vbuf[e] written
// at natural edge position -> sequential stores, coverage independent of the
// sort. Block's 4 waves share 32 edges, own disjoint 64B column chunks.
// ---------------------------------------------------------------------------
__global__ __launch_bounds__(256, 3) void edge_mlp(
    const float* __restrict__ x, const float* __restrict__ ea,
    const float* __restrict__ bases, const int* __restrict__ src,
    const float* __restrict__ W1, const float* __restrict__ b1,
    unsigned short* __restrict__ vbuf, int E, int ntiles)
{
    const int tid = threadIdx.x;
    const int w = tid >> 6, l = tid & 63, lg = l >> 4, lr = l & 15;

    // W1 A-fragments for this wave's two 16-col n-tiles (cols w*32 .. +32).
    bf16x8 wf[2][4];
    f32x4 b1v[2];
#pragma unroll
    for (int ni = 0; ni < 2; ++ni) {
        int row = w * 32 + ni * 16 + lr;
#pragma unroll
        for (int kk = 0; kk < 4; ++kk) {
            const float* p = W1 + row * H + kk * 32 + lg * 8;
            u16x8 tt;
#pragma unroll
            for (int i = 0; i < 8; ++i) tt[i] = f2bfu(p[i]);
            wf[ni][kk] = __builtin_bit_cast(bf16x8, tt);
        }
        b1v[ni] = *reinterpret_cast<const f32x4*>(b1 + w * 32 + ni * 16 + lg * 4);
    }

    for (int t = blockIdx.x; t < ntiles; t += gridDim.x) {
        const int e0 = t * 32;
#pragma unroll
        for (int s = 0; s < 2; ++s) {
            const int es = e0 + s * 16 + lr;
            const int ec = es < E ? es : E - 1;
            const int sv = src[ec];
            const float* pea = ea + (long)ec * H + lg * 8;
            const float* pxx = x + (long)sv * H + lg * 8;

            // raw loads: 8 contiguous floats per kk from each source
            f32x4 re[8], rx[8];
#pragma unroll
            for (int kk = 0; kk < 4; ++kk) {
                re[kk * 2]     = *reinterpret_cast<const f32x4*>(pea + kk * 32);
                re[kk * 2 + 1] = *reinterpret_cast<const f32x4*>(pea + kk * 32 + 4);
                rx[kk * 2]     = *reinterpret_cast<const f32x4*>(pxx + kk * 32);
                rx[kk * 2 + 1] = *reinterpret_cast<const f32x4*>(pxx + kk * 32 + 4);
            }
            // bases for the epilogue (both n-tiles of this wave)
            f32x4 bs0 = *reinterpret_cast<const f32x4*>(bases + (long)ec * H + w * 32 + lg * 4);
            f32x4 bs1 = *reinterpret_cast<const f32x4*>(bases + (long)ec * H + w * 32 + 16 + lg * 4);

            // convert posE = ea + x[src] to bf16 fragments
            bf16x8 af[4];
#pragma unroll
            for (int kk = 0; kk < 4; ++kk) {
                u16x8 o;
#pragma unroll
                for (int i = 0; i < 4; ++i) {
                    o[i]     = f2bfu(re[kk * 2][i]     + rx[kk * 2][i]);
                    o[i + 4] = f2bfu(re[kk * 2 + 1][i] + rx[kk * 2 + 1][i]);
                }
                af[kk] = __builtin_bit_cast(bf16x8, o);
            }

            // MFMA + epilogue (store guarded; MFMA unguarded — all lanes)
#pragma unroll
            for (int ni = 0; ni < 2; ++ni) {
                f32x4 a4 = {0.f, 0.f, 0.f, 0.f};
#pragma unroll
                for (int kk = 0; kk < 4; ++kk)
                    a4 = __builtin_amdgcn_mfma_f32_16x16x32_bf16(wf[ni][kk], af[kk], a4, 0, 0, 0);
                if (es < E) {
                    const f32x4 bs = ni ? bs1 : bs0;
                    u16x4 o;
#pragma unroll
                    for (int r = 0; r < 4; ++r)
                        o[r] = f2bfu(gelu_exact(a4[r] + b1v[ni][r]) * bs[r]);
                    *reinterpret_cast<u16x4*>(vbuf + (size_t)es * H + w * 32 + ni * 16 + lg * 4) = o;
                }
            }
        }
    }
}

// ---------------------------------------------------------------------------
// Phase B: segment-sum gathering dst-grouped rows via perm. One wave per
// node; each row is a contiguous 256B read (64 lanes x u32); vbuf is
// L3-resident (164 MB). 4-row unroll for load concurrency.
// ---------------------------------------------------------------------------
__global__ __launch_bounds__(256) void aggregate_kernel(
    const unsigned short* __restrict__ vbuf, const int* __restrict__ perm,
    const int* __restrict__ offs, float* __restrict__ aggr, int Nn, int E)
{
    const int wv = threadIdx.x >> 6, lane = threadIdx.x & 63;
    const int n = blockIdx.x * 4 + wv;
    if (n >= Nn) return;
    const int lo = offs[n], hi = offs[n + 1];
    float a0 = 0.f, a1 = 0.f;
    int i = lo;
    for (; i + 3 < hi; i += 4) {
        int e0 = perm[i], e1 = perm[i + 1], e2 = perm[i + 2], e3 = perm[i + 3];
        e0 = (unsigned)e0 < (unsigned)E ? e0 : 0;
        e1 = (unsigned)e1 < (unsigned)E ? e1 : 0;
        e2 = (unsigned)e2 < (unsigned)E ? e2 : 0;
        e3 = (unsigned)e3 < (unsigned)E ? e3 : 0;
        unsigned u0 = *reinterpret_cast<const unsigned*>(vbuf + (size_t)e0 * H + lane * 2);
        unsigned u1 = *reinterpret_cast<const unsigned*>(vbuf + (size_t)e1 * H + lane * 2);
        unsigned u2 = *reinterpret_cast<const unsigned*>(vbuf + (size_t)e2 * H + lane * 2);
        unsigned u3 = *reinterpret_cast<const unsigned*>(vbuf + (size_t)e3 * H + lane * 2);
        a0 += __builtin_bit_cast(float, u0 << 16) + __builtin_bit_cast(float, u1 << 16)
            + __builtin_bit_cast(float, u2 << 16) + __builtin_bit_cast(float, u3 << 16);
        a1 += __builtin_bit_cast(float, u0 & 0xffff0000u) + __builtin_bit_cast(float, u1 & 0xffff0000u)
            + __builtin_bit_cast(float, u2 & 0xffff0000u) + __builtin_bit_cast(float, u3 & 0xffff0000u);
    }
    for (; i < hi; ++i) {
        int e = perm[i];
        e = (unsigned)e < (unsigned)E ? e : 0;
        unsigned u0 = *reinterpret_cast<const unsigned*>(vbuf + (size_t)e * H + lane * 2);
        a0 += __builtin_bit_cast(float, u0 << 16);
        a1 += __builtin_bit_cast(float, u0 & 0xffff0000u);
    }
    f32x2 o = {a0, a1};
    *reinterpret_cast<f32x2*>(aggr + (size_t)n * H + lane * 2) = o;
}

// ---------------------------------------------------------------------------
// Node GEMM  Y = f(A) @ W^T + bias, fused column sum/sumsq epilogue for BN
// stats. PRE=true applies gelu(a*scale+shift) on load.
// ---------------------------------------------------------------------------
template <bool PRE>
__global__ __launch_bounds__(256) void node_gemm(
    const float* __restrict__ A, const float* __restrict__ W,
    const float* __restrict__ bias, const float* __restrict__ scl,
    const float* __restrict__ shf, float* __restrict__ Y,
    float* __restrict__ csum, float* __restrict__ cssq, int Nn)
{
    __shared__ __align__(16) unsigned short alds[64 * 128];

    const int tid = threadIdx.x;
    const int w = tid >> 6, l = tid & 63, lg = l >> 4, lr = l & 15;
    const int er = tid >> 2, q = tid & 3;
    const int r0 = blockIdx.x * 64;

    bf16x8 bf[2][4];
    float bv[2];
#pragma unroll
    for (int n = 0; n < 2; ++n) {
        int row = w * 32 + n * 16 + lr;
        bv[n] = bias[row];
#pragma unroll
        for (int kk = 0; kk < 4; ++kk) {
            const float* p = W + row * H + kk * 32 + lg * 8;
            u16x8 t;
#pragma unroll
            for (int i = 0; i < 8; ++i) t[i] = f2bfu(p[i]);
            bf[n][kk] = __builtin_bit_cast(bf16x8, t);
        }
    }

    {
        int rr = r0 + er;
        int rc = rr < Nn ? rr : Nn - 1;
        const f32x4* pa = reinterpret_cast<const f32x4*>(A + (long)rc * H + q * 32);
        const int swz = (er & 7) << 3;
#pragma unroll
        for (int i = 0; i < 8; ++i) {
            f32x4 v = pa[i];
            if constexpr (PRE) {
                f32x4 sc = *reinterpret_cast<const f32x4*>(scl + q * 32 + i * 4);
                f32x4 sh = *reinterpret_cast<const f32x4*>(shf + q * 32 + i * 4);
#pragma unroll
                for (int c = 0; c < 4; ++c) v[c] = gelu_exact(v[c] * sc[c] + sh[c]);
            }
            u16x4 o;
            o[0] = f2bfu(v[0]);
            o[1] = f2bfu(v[1]);
            o[2] = f2bfu(v[2]);
            o[3] = f2bfu(v[3]);
            int col = q * 32 + i * 4;
            *reinterpret_cast<u16x4*>(&alds[er * 128 + (col ^ swz)]) = o;
        }
    }
    __syncthreads();

    float ps[2] = {0.f, 0.f}, ps2[2] = {0.f, 0.f};
#pragma unroll
    for (int m = 0; m < 4; ++m) {
        const int arow = m * 16 + lr;
        const int aswz = (arow & 7) << 3;
        bf16x8 af[4];
#pragma unroll
        for (int kk = 0; kk < 4; ++kk)
            af[kk] = __builtin_bit_cast(bf16x8,
                *reinterpret_cast<const u16x8*>(&alds[arow * 128 + ((kk * 32 + lg * 8) ^ aswz)]));
#pragma unroll
        for (int n = 0; n < 2; ++n) {
            f32x4 a4 = {0.f, 0.f, 0.f, 0.f};
#pragma unroll
            for (int kk = 0; kk < 4; ++kk)
                a4 = __builtin_amdgcn_mfma_f32_16x16x32_bf16(af[kk], bf[n][kk], a4, 0, 0, 0);
            const int j = w * 32 + n * 16 + lr;
#pragma unroll
            for (int r = 0; r < 4; ++r) {
                int rr = r0 + m * 16 + lg * 4 + r;
                if (rr < Nn) {
                    float z = a4[r] + bv[n];
                    Y[(long)rr * H + j] = z;
                    ps[n] += z;
                    ps2[n] += z * z;
                }
            }
        }
    }
#pragma unroll
    for (int n = 0; n < 2; ++n) {
        float s = ps[n];
        s += __shfl_xor(s, 16);
        s += __shfl_xor(s, 32);
        float s2 = ps2[n];
        s2 += __shfl_xor(s2, 16);
        s2 += __shfl_xor(s2, 32);
        if (lg == 0) {
            int j = w * 32 + n * 16 + lr;
            atomicAdd(&csum[j], s);
            atomicAdd(&cssq[j], s2);
        }
    }
}

__global__ void finalize_bn(const float* __restrict__ csum, const float* __restrict__ cssq,
                            const float* __restrict__ g, const float* __restrict__ be,
                            float* __restrict__ scl, float* __restrict__ shf, float invN)
{
    int j = threadIdx.x;
    float mu = csum[j] * invN;
    float var = fmaxf(cssq[j] * invN - mu * mu, 0.f);
    float s = g[j] * rsqrtf(var + EPS);
    scl[j] = s;
    shf[j] = be[j] - mu * s;
}

__global__ __launch_bounds__(256) void final_gelu(
    const float* __restrict__ Y2, const float* __restrict__ scl,
    const float* __restrict__ shf, float* __restrict__ out, long n4)
{
    long i = (long)blockIdx.x * blockDim.x + threadIdx.x;
    const long stride = (long)gridDim.x * blockDim.x;
    for (; i < n4; i += stride) {
        f32x4 v = reinterpret_cast<const f32x4*>(Y2)[i];
        int c4 = (int)(i & 31);
        f32x4 sc = reinterpret_cast<const f32x4*>(scl)[c4];
        f32x4 sh = reinterpret_cast<const f32x4*>(shf)[c4];
        f32x4 o;
#pragma unroll
        for (int c = 0; c < 4; ++c) o[c] = gelu_exact(v[c] * sc[c] + sh[c]);
        reinterpret_cast<f32x4*>(out)[i] = o;
    }
}

extern "C" void kernel_launch(void* const* d_in, const int* in_sizes, int n_in,
                              void* d_out, int out_size, void* d_ws, size_t ws_size,
                              hipStream_t stream) {
    const float* x     = (const float*)d_in[0];
    const float* ea    = (const float*)d_in[1];
    const float* bases = (const float*)d_in[2];
    const int*   src   = (const int*)d_in[3];
    const int*   dst   = (const int*)d_in[4];
    const float* W1    = (const float*)d_in[5];
    const float* b1    = (const float*)d_in[6];
    const float* W2    = (const float*)d_in[7];
    const float* b2    = (const float*)d_in[8];
    const float* g1    = (const float*)d_in[9];
    const float* be1   = (const float*)d_in[10];
    const float* W3    = (const float*)d_in[11];
    const float* b3    = (const float*)d_in[12];
    const float* g2    = (const float*)d_in[13];
    const float* be2   = (const float*)d_in[14];

    const int N = in_sizes[0] / H;
    const int E = in_sizes[1] / H;

    float* ws    = (float*)d_ws;
    float* aggr  = ws;                        // [N,H]; reused as y2
    float* y1    = aggr + (size_t)N * H;      // [N,H]
    float* stats = y1 + (size_t)N * H;        // 1024 floats
    float* sum1 = stats,        *ss1 = stats + 128;
    float* sum2 = stats + 256,  *ss2 = stats + 384;
    float* scl1 = stats + 512,  *shf1 = stats + 640;
    float* scl2 = stats + 768,  *shf2 = stats + 896;
    int* cnt  = (int*)(stats + 1024);         // [N] histogram
    int* cnt2 = cnt + N;                      // [N] scatter cursor (zeroed)
    int* perm = cnt2 + N;                     // [E]
    int* offs = perm + E;                     // [N+1]
    unsigned short* vbuf = (unsigned short*)(((uintptr_t)(offs + N + 1) + 4095) & ~(uintptr_t)4095); // [E,H] bf16, 4KB-aligned

    // one DMA memset covers stats (1024 f32) + cnt (N) + cnt2 (N)
    hipMemsetAsync(stats, 0, (size_t)(1024 + 2 * N) * sizeof(float), stream);

    // --- counting sort (perm + offs) ---
    hist_kernel<<<2048, 256, 0, stream>>>(dst, cnt, E);
    scan_kernel<<<1, 1024, 0, stream>>>(cnt, offs, N, E);
    scatter_perm<<<2048, 256, 0, stream>>>(dst, offs, cnt2, perm, E);

    // --- Phase A: barrier-free streaming edge MLP (natural-order writes) ---
    const int ntiles = (E + 31) / 32;
    edge_mlp<<<2048, 256, 0, stream>>>(x, ea, bases, src, W1, b1, vbuf, E, ntiles);

    // --- Phase B: segment sum (gather via perm) ---
    aggregate_kernel<<<(N + 3) / 4, 256, 0, stream>>>(vbuf, perm, offs, aggr, N, E);

    // --- node pipeline ---
    const int nblk = (N + 63) / 64;
    node_gemm<false><<<nblk, 256, 0, stream>>>(aggr, W2, b2, nullptr, nullptr, y1, sum1, ss1, N);
    finalize_bn<<<1, 128, 0, stream>>>(sum1, ss1, g1, be1, scl1, shf1, 1.0f / (float)N);
    node_gemm<true><<<nblk, 256, 0, stream>>>(y1, W3, b3, scl1, shf1, aggr, sum2, ss2, N);
    finalize_bn<<<1, 128, 0, stream>>>(sum2, ss2, g2, be2, scl2, shf2, 1.0f / (float)N);

    long n4 = (long)N * H / 4;
    final_gelu<<<2048, 256, 0, stream>>>(aggr, scl2, shf2, (float*)d_out, n4);
}

// Round 7
// 541.509 us; speedup vs baseline: 1.1528x; 1.1528x over previous
//
#include <hip/hip_runtime.h>
#include <cmath>

#define H 128
#define EPS 1e-5f

typedef __attribute__((ext_vector_type(8))) __bf16 bf16x8;
typedef __attribute__((ext_vector_type(4))) float f32x4;
typedef __attribute__((ext_vector_type(2))) float f32x2;
typedef __attribute__((ext_vector_type(4))) unsigned short u16x4;
typedef __attribute__((ext_vector_type(8))) unsigned short u16x8;

__device__ __forceinline__ float gelu_exact(float x) {
    return 0.5f * x * (1.0f + erff(x * 0.70710678118654752f));
}

__device__ __forceinline__ unsigned short f2bfu(float f) {
    __bf16 h = (__bf16)f;   // RNE fptrunc
    return __builtin_bit_cast(unsigned short, h);
}

// ---------------------------------------------------------------------------
// Counting sort of edges by dst -> perm (dst-grouped edge ids), offs.
// ---------------------------------------------------------------------------
__global__ __launch_bounds__(256) void hist_kernel(const int* __restrict__ dst,
                                                   int* __restrict__ cnt, int E)
{
    int i = blockIdx.x * blockDim.x + threadIdx.x;
    const int stride = gridDim.x * blockDim.x;
    for (; i < E; i += stride) atomicAdd(&cnt[dst[i]], 1);
}

__global__ __launch_bounds__(1024) void scan_kernel(const int* __restrict__ cnt,
                                                    int* __restrict__ offs,
                                                    int Nn, int E)
{
    __shared__ int part[1024];
    const int t = threadIdx.x;
    const int CH = (Nn + 1023) / 1024;
    const int base = t * CH;
    int s = 0;
    for (int i = 0; i < CH; ++i) {
        int idx = base + i;
        if (idx < Nn) s += cnt[idx];
    }
    part[t] = s;
    __syncthreads();
    for (int d = 1; d < 1024; d <<= 1) {
        int v = (t >= d) ? part[t - d] : 0;
        __syncthreads();
        part[t] += v;
        __syncthreads();
    }
    int run = (t > 0) ? part[t - 1] : 0;
    for (int i = 0; i < CH; ++i) {
        int idx = base + i;
        if (idx < Nn) {
            offs[idx] = run;
            run += cnt[idx];
        }
    }
    if (t == 0) offs[Nn] = E;
}

__global__ __launch_bounds__(256) void scatter_perm(const int* __restrict__ dst,
                                                    const int* __restrict__ offs,
                                                    int* __restrict__ cur2,
                                                    int* __restrict__ perm, int E)
{
    int i = blockIdx.x * blockDim.x + threadIdx.x;
    const int stride = gridDim.x * blockDim.x;
    for (; i < E; i += stride) {
        int n = dst[i];
        int p = offs[n] + atomicAdd(&cur2[n], 1);
        perm[p] = i;
    }
}

// ---------------------------------------------------------------------------
// A1: posE = bf16(x[src] + ea), natural edge order. Pure streaming:
// thread i handles one 8-element chunk (32B in, 16B out), fully coalesced.
// ---------------------------------------------------------------------------
__global__ __launch_bounds__(256) void build_pose(
    const float* __restrict__ x, const float* __restrict__ ea,
    const int* __restrict__ src, unsigned short* __restrict__ pose,
    long nchunks)
{
    long i = (long)blockIdx.x * blockDim.x + threadIdx.x;
    const long stride = (long)gridDim.x * blockDim.x;
    for (; i < nchunks; i += stride) {
        const long e = i >> 4;          // edge id
        const int c8 = (int)(i & 15);   // 8-elem chunk within row
        const int s = src[e];           // broadcast across 16 threads (L1)
        const f32x4* pe = reinterpret_cast<const f32x4*>(ea + e * H + c8 * 8);
        const f32x4* px = reinterpret_cast<const f32x4*>(x + (long)s * H + c8 * 8);
        f32x4 a0 = pe[0], a1 = pe[1];
        f32x4 b0 = px[0], b1 = px[1];
        u16x8 o;
#pragma unroll
        for (int j = 0; j < 4; ++j) {
            o[j]     = f2bfu(a0[j] + b0[j]);
            o[j + 4] = f2bfu(a1[j] + b1[j]);
        }
        *reinterpret_cast<u16x8*>(pose + i * 8) = o;
    }
}

// ---------------------------------------------------------------------------
// A2: g = gelu(posE @ W1^T + b1) as bf16, IN PLACE over posE.
// One 64-edge tile per block (grid = E/64, no loop). Stage = contiguous
// u16x8 loads + XOR-swizzled ds_write (zero conversion VALU). Compute =
// swapped-operand MFMA (lane owns edge lr, 4 consecutive out-cols).
// In-place is safe: all reads of this block's rows complete before the
// barrier; rows are block-disjoint.
// ---------------------------------------------------------------------------
__global__ __launch_bounds__(256) void edge_gemm(
    unsigned short* __restrict__ pose, const float* __restrict__ W1,
    const float* __restrict__ b1, int E)
{
    __shared__ __align__(16) unsigned short alds[64 * 128];  // 16 KB

    const int tid = threadIdx.x;
    const int w = tid >> 6, l = tid & 63, lg = l >> 4, lr = l & 15;

    // W1 A-fragments: rows w*32 + ni*16 + lr, k = kk*32 + lg*8 .. +8
    bf16x8 wf[2][4];
    f32x4 b1v[2];
#pragma unroll
    for (int ni = 0; ni < 2; ++ni) {
        int row = w * 32 + ni * 16 + lr;
#pragma unroll
        for (int kk = 0; kk < 4; ++kk) {
            const float* p = W1 + row * H + kk * 32 + lg * 8;
            u16x8 tt;
#pragma unroll
            for (int i = 0; i < 8; ++i) tt[i] = f2bfu(p[i]);
            wf[ni][kk] = __builtin_bit_cast(bf16x8, tt);
        }
        b1v[ni] = *reinterpret_cast<const f32x4*>(b1 + w * 32 + ni * 16 + lg * 4);
    }

    const int e0 = blockIdx.x * 64;   // E % 64 == 0 for this problem; guard anyway
    // ---- stage 64x128 bf16 tile, contiguous loads, swizzled ds_write ----
#pragma unroll
    for (int it = 0; it < 4; ++it) {
        const int gch = it * 256 + tid;          // 16B-chunk id, 0..1023
        const int row = gch >> 4, c16 = gch & 15;
        const int er = e0 + row;
        const int ec = er < E ? er : E - 1;
        u16x8 v = *reinterpret_cast<const u16x8*>(pose + (size_t)ec * H + c16 * 8);
        const int sc16 = c16 ^ (row & 7);
        *reinterpret_cast<u16x8*>(&alds[row * 128 + sc16 * 8]) = v;
    }
    __syncthreads();

    // ---- compute + epilogue (no bases here; deferred to aggregate) ----
#pragma unroll
    for (int s = 0; s < 4; ++s) {
        const int arow = s * 16 + lr;
        const int aswz = (arow & 7) << 3;
        bf16x8 af[4];
#pragma unroll
        for (int kk = 0; kk < 4; ++kk)
            af[kk] = __builtin_bit_cast(bf16x8,
                *reinterpret_cast<const u16x8*>(&alds[arow * 128 + ((kk * 32 + lg * 8) ^ aswz)]));
        const int es = e0 + s * 16 + lr;
#pragma unroll
        for (int ni = 0; ni < 2; ++ni) {
            f32x4 a4 = {0.f, 0.f, 0.f, 0.f};
#pragma unroll
            for (int kk = 0; kk < 4; ++kk)
                a4 = __builtin_amdgcn_mfma_f32_16x16x32_bf16(wf[ni][kk], af[kk], a4, 0, 0, 0);
            if (es < E) {
                u16x4 o;
#pragma unroll
                for (int r = 0; r < 4; ++r)
                    o[r] = f2bfu(gelu_exact(a4[r] + b1v[ni][r]));
                *reinterpret_cast<u16x4*>(pose + (size_t)es * H + w * 32 + ni * 16 + lg * 4) = o;
            }
        }
    }
}

// ---------------------------------------------------------------------------
// Phase B: aggr[n] = sum_{e in group(n)} g[e] * bases[e].
// One wave per node; per edge: g row (u32/lane) + bases row (f32x2/lane),
// both full-row coalesced; random row ORDER only. 4-row unroll.
// ---------------------------------------------------------------------------
__global__ __launch_bounds__(256) void aggregate_kernel(
    const unsigned short* __restrict__ gbuf, const float* __restrict__ bases,
    const int* __restrict__ perm, const int* __restrict__ offs,
    float* __restrict__ aggr, int Nn, int E)
{
    const int wv = threadIdx.x >> 6, lane = threadIdx.x & 63;
    const int n = blockIdx.x * 4 + wv;
    if (n >= Nn) return;
    const int lo = offs[n], hi = offs[n + 1];
    float a0 = 0.f, a1 = 0.f;
    int i = lo;
    for (; i + 3 < hi; i += 4) {
        int e0 = perm[i], e1 = perm[i + 1], e2 = perm[i + 2], e3 = perm[i + 3];
        e0 = (unsigned)e0 < (unsigned)E ? e0 : 0;
        e1 = (unsigned)e1 < (unsigned)E ? e1 : 0;
        e2 = (unsigned)e2 < (unsigned)E ? e2 : 0;
        e3 = (unsigned)e3 < (unsigned)E ? e3 : 0;
        unsigned u0 = *reinterpret_cast<const unsigned*>(gbuf + (size_t)e0 * H + lane * 2);
        unsigned u1 = *reinterpret_cast<const unsigned*>(gbuf + (size_t)e1 * H + lane * 2);
        unsigned u2 = *reinterpret_cast<const unsigned*>(gbuf + (size_t)e2 * H + lane * 2);
        unsigned u3 = *reinterpret_cast<const unsigned*>(gbuf + (size_t)e3 * H + lane * 2);
        f32x2 b0 = *reinterpret_cast<const f32x2*>(bases + (size_t)e0 * H + lane * 2);
        f32x2 b1_ = *reinterpret_cast<const f32x2*>(bases + (size_t)e1 * H + lane * 2);
        f32x2 b2 = *reinterpret_cast<const f32x2*>(bases + (size_t)e2 * H + lane * 2);
        f32x2 b3 = *reinterpret_cast<const f32x2*>(bases + (size_t)e3 * H + lane * 2);
        a0 += __builtin_bit_cast(float, u0 << 16) * b0[0]
            + __builtin_bit_cast(float, u1 << 16) * b1_[0]
            + __builtin_bit_cast(float, u2 << 16) * b2[0]
            + __builtin_bit_cast(float, u3 << 16) * b3[0];
        a1 += __builtin_bit_cast(float, u0 & 0xffff0000u) * b0[1]
            + __builtin_bit_cast(float, u1 & 0xffff0000u) * b1_[1]
            + __builtin_bit_cast(float, u2 & 0xffff0000u) * b2[1]
            + __builtin_bit_cast(float, u3 & 0xffff0000u) * b3[1];
    }
    for (; i < hi; ++i) {
        int e = perm[i];
        e = (unsigned)e < (unsigned)E ? e : 0;
        unsigned u0 = *reinterpret_cast<const unsigned*>(gbuf + (size_t)e * H + lane * 2);
        f32x2 b0 = *reinterpret_cast<const f32x2*>(bases + (size_t)e * H + lane * 2);
        a0 += __builtin_bit_cast(float, u0 << 16) * b0[0];
        a1 += __builtin_bit_cast(float, u0 & 0xffff0000u) * b0[1];
    }
    f32x2 o = {a0, a1};
    *reinterpret_cast<f32x2*>(aggr + (size_t)n * H + lane * 2) = o;
}

// ---------------------------------------------------------------------------
// Node GEMM  Y = f(A) @ W^T + bias, fused column sum/sumsq epilogue for BN
// stats. PRE=true applies gelu(a*scale+shift) on load.
// ---------------------------------------------------------------------------
template <bool PRE>
__global__ __launch_bounds__(256) void node_gemm(
    const float* __restrict__ A, const float* __restrict__ W,
    const float* __restrict__ bias, const float* __restrict__ scl,
    const float* __restrict__ shf, float* __restrict__ Y,
    float* __restrict__ csum, float* __restrict__ cssq, int Nn)
{
    __shared__ __align__(16) unsigned short alds[64 * 128];

    const int tid = threadIdx.x;
    const int w = tid >> 6, l = tid & 63, lg = l >> 4, lr = l & 15;
    const int er = tid >> 2, q = tid & 3;
    const int r0 = blockIdx.x * 64;

    bf16x8 bf[2][4];
    float bv[2];
#pragma unroll
    for (int n = 0; n < 2; ++n) {
        int row = w * 32 + n * 16 + lr;
        bv[n] = bias[row];
#pragma unroll
        for (int kk = 0; kk < 4; ++kk) {
            const float* p = W + row * H + kk * 32 + lg * 8;
            u16x8 t;
#pragma unroll
            for (int i = 0; i < 8; ++i) t[i] = f2bfu(p[i]);
            bf[n][kk] = __builtin_bit_cast(bf16x8, t);
        }
    }

    {
        int rr = r0 + er;
        int rc = rr < Nn ? rr : Nn - 1;
        const f32x4* pa = reinterpret_cast<const f32x4*>(A + (long)rc * H + q * 32);
        const int swz = (er & 7) << 3;
#pragma unroll
        for (int i = 0; i < 8; ++i) {
            f32x4 v = pa[i];
            if constexpr (PRE) {
                f32x4 sc = *reinterpret_cast<const f32x4*>(scl + q * 32 + i * 4);
                f32x4 sh = *reinterpret_cast<const f32x4*>(shf + q * 32 + i * 4);
#pragma unroll
                for (int c = 0; c < 4; ++c) v[c] = gelu_exact(v[c] * sc[c] + sh[c]);
            }
            u16x4 o;
            o[0] = f2bfu(v[0]);
            o[1] = f2bfu(v[1]);
            o[2] = f2bfu(v[2]);
            o[3] = f2bfu(v[3]);
            int col = q * 32 + i * 4;
            *reinterpret_cast<u16x4*>(&alds[er * 128 + (col ^ swz)]) = o;
        }
    }
    __syncthreads();

    float ps[2] = {0.f, 0.f}, ps2[2] = {0.f, 0.f};
#pragma unroll
    for (int m = 0; m < 4; ++m) {
        const int arow = m * 16 + lr;
        const int aswz = (arow & 7) << 3;
        bf16x8 af[4];
#pragma unroll
        for (int kk = 0; kk < 4; ++kk)
            af[kk] = __builtin_bit_cast(bf16x8,
                *reinterpret_cast<const u16x8*>(&alds[arow * 128 + ((kk * 32 + lg * 8) ^ aswz)]));
#pragma unroll
        for (int n = 0; n < 2; ++n) {
            f32x4 a4 = {0.f, 0.f, 0.f, 0.f};
#pragma unroll
            for (int kk = 0; kk < 4; ++kk)
                a4 = __builtin_amdgcn_mfma_f32_16x16x32_bf16(af[kk], bf[n][kk], a4, 0, 0, 0);
            const int j = w * 32 + n * 16 + lr;
#pragma unroll
            for (int r = 0; r < 4; ++r) {
                int rr = r0 + m * 16 + lg * 4 + r;
                if (rr < Nn) {
                    float z = a4[r] + bv[n];
                    Y[(long)rr * H + j] = z;
                    ps[n] += z;
                    ps2[n] += z * z;
                }
            }
        }
    }
#pragma unroll
    for (int n = 0; n < 2; ++n) {
        float s = ps[n];
        s += __shfl_xor(s, 16);
        s += __shfl_xor(s, 32);
        float s2 = ps2[n];
        s2 += __shfl_xor(s2, 16);
        s2 += __shfl_xor(s2, 32);
        if (lg == 0) {
            int j = w * 32 + n * 16 + lr;
            atomicAdd(&csum[j], s);
            atomicAdd(&cssq[j], s2);
        }
    }
}

__global__ void finalize_bn(const float* __restrict__ csum, const float* __restrict__ cssq,
                            const float* __restrict__ g, const float* __restrict__ be,
                            float* __restrict__ scl, float* __restrict__ shf, float invN)
{
    int j = threadIdx.x;
    float mu = csum[j] * invN;
    float var = fmaxf(cssq[j] * invN - mu * mu, 0.f);
    float s = g[j] * rsqrtf(var + EPS);
    scl[j] = s;
    shf[j] = be[j] - mu * s;
}

__global__ __launch_bounds__(256) void final_gelu(
    const float* __restrict__ Y2, const float* __restrict__ scl,
    const float* __restrict__ shf, float* __restrict__ out, long n4)
{
    long i = (long)blockIdx.x * blockDim.x + threadIdx.x;
    const long stride = (long)gridDim.x * blockDim.x;
    for (; i < n4; i += stride) {
        f32x4 v = reinterpret_cast<const f32x4*>(Y2)[i];
        int c4 = (int)(i & 31);
        f32x4 sc = reinterpret_cast<const f32x4*>(scl)[c4];
        f32x4 sh = reinterpret_cast<const f32x4*>(shf)[c4];
        f32x4 o;
#pragma unroll
        for (int c = 0; c < 4; ++c) o[c] = gelu_exact(v[c] * sc[c] + sh[c]);
        reinterpret_cast<f32x4*>(out)[i] = o;
    }
}

extern "C" void kernel_launch(void* const* d_in, const int* in_sizes, int n_in,
                              void* d_out, int out_size, void* d_ws, size_t ws_size,
                              hipStream_t stream) {
    const float* x     = (const float*)d_in[0];
    const float* ea    = (const float*)d_in[1];
    const float* bases = (const float*)d_in[2];
    const int*   src   = (const int*)d_in[3];
    const int*   dst   = (const int*)d_in[4];
    const float* W1    = (const float*)d_in[5];
    const float* b1    = (const float*)d_in[6];
    const float* W2    = (const float*)d_in[7];
    const float* b2    = (const float*)d_in[8];
    const float* g1    = (const float*)d_in[9];
    const float* be1   = (const float*)d_in[10];
    const float* W3    = (const float*)d_in[11];
    const float* b3    = (const float*)d_in[12];
    const float* g2    = (const float*)d_in[13];
    const float* be2   = (const float*)d_in[14];

    const int N = in_sizes[0] / H;
    const int E = in_sizes[1] / H;

    float* ws    = (float*)d_ws;
    float* aggr  = ws;                        // [N,H]; reused as y2
    float* y1    = aggr + (size_t)N * H;      // [N,H]
    float* stats = y1 + (size_t)N * H;        // 1024 floats
    float* sum1 = stats,        *ss1 = stats + 128;
    float* sum2 = stats + 256,  *ss2 = stats + 384;
    float* scl1 = stats + 512,  *shf1 = stats + 640;
    float* scl2 = stats + 768,  *shf2 = stats + 896;
    int* cnt  = (int*)(stats + 1024);         // [N] histogram
    int* cnt2 = cnt + N;                      // [N] scatter cursor (zeroed)
    int* perm = cnt2 + N;                     // [E]
    int* offs = perm + E;                     // [N+1]
    unsigned short* pose = (unsigned short*)(((uintptr_t)(offs + N + 1) + 4095) & ~(uintptr_t)4095); // [E,H] bf16; reused in-place as g

    // one DMA memset covers stats (1024 f32) + cnt (N) + cnt2 (N)
    hipMemsetAsync(stats, 0, (size_t)(1024 + 2 * N) * sizeof(float), stream);

    // --- counting sort (perm + offs) ---
    hist_kernel<<<2048, 256, 0, stream>>>(dst, cnt, E);
    scan_kernel<<<1, 1024, 0, stream>>>(cnt, offs, N, E);
    scatter_perm<<<2048, 256, 0, stream>>>(dst, offs, cnt2, perm, E);

    // --- A1: posE = bf16(x[src] + ea), streaming ---
    const long nchunks = (long)E * (H / 8);
    build_pose<<<4096, 256, 0, stream>>>(x, ea, src, pose, nchunks);

    // --- A2: g = gelu(posE @ W1^T + b1), in place ---
    edge_gemm<<<(E + 63) / 64, 256, 0, stream>>>(pose, W1, b1, E);

    // --- Phase B: aggr = segment-sum(g * bases) via perm gather ---
    aggregate_kernel<<<(N + 3) / 4, 256, 0, stream>>>(pose, bases, perm, offs, aggr, N, E);

    // --- node pipeline ---
    const int nblk = (N + 63) / 64;
    node_gemm<false><<<nblk, 256, 0, stream>>>(aggr, W2, b2, nullptr, nullptr, y1, sum1, ss1, N);
    finalize_bn<<<1, 128, 0, stream>>>(sum1, ss1, g1, be1, scl1, shf1, 1.0f / (float)N);
    node_gemm<true><<<nblk, 256, 0, stream>>>(y1, W3, b3, scl1, shf1, aggr, sum2, ss2, N);
    finalize_bn<<<1, 128, 0, stream>>>(sum2, ss2, g2, be2, scl2, shf2, 1.0f / (float)N);

    long n4 = (long)N * H / 4;
    final_gelu<<<2048, 256, 0, stream>>>(aggr, scl2, shf2, (float*)d_out, n4);
}

// Round 8
// 479.289 us; speedup vs baseline: 1.3025x; 1.1298x over previous
//
#include <hip/hip_runtime.h>
#include <cmath>

#define H 128
#define EPS 1e-5f

typedef __attribute__((ext_vector_type(8))) __bf16 bf16x8;
typedef __attribute__((ext_vector_type(4))) float f32x4;
typedef __attribute__((ext_vector_type(2))) float f32x2;
typedef __attribute__((ext_vector_type(4))) unsigned short u16x4;
typedef __attribute__((ext_vector_type(8))) unsigned short u16x8;
typedef __attribute__((ext_vector_type(4))) int i32x4;

__device__ __forceinline__ float gelu_exact(float x) {
    return 0.5f * x * (1.0f + erff(x * 0.70710678118654752f));
}

__device__ __forceinline__ unsigned short f2bfu(float f) {
    __bf16 h = (__bf16)f;   // RNE fptrunc
    return __builtin_bit_cast(unsigned short, h);
}

// ---------------------------------------------------------------------------
// Zero scratch (stats + cnt + cnt2) — replaces the pathologically slow
// in-graph hipMemsetAsync (measured 195 us for 324 KB in R7).
// ---------------------------------------------------------------------------
__global__ __launch_bounds__(256) void zero_kernel(int* __restrict__ p, int n4)
{
    int i = blockIdx.x * blockDim.x + threadIdx.x;
    const int stride = gridDim.x * blockDim.x;
    i32x4 z = {0, 0, 0, 0};
    for (; i < n4; i += stride)
        reinterpret_cast<i32x4*>(p)[i] = z;
}

// ---------------------------------------------------------------------------
// Counting sort of edges by dst -> perm (dst-grouped edge ids), offs.
// ---------------------------------------------------------------------------
__global__ __launch_bounds__(256) void hist_kernel(const int* __restrict__ dst,
                                                   int* __restrict__ cnt, int E)
{
    int i = blockIdx.x * blockDim.x + threadIdx.x;
    const int stride = gridDim.x * blockDim.x;
    for (; i < E; i += stride) atomicAdd(&cnt[dst[i]], 1);
}

__global__ __launch_bounds__(1024) void scan_kernel(const int* __restrict__ cnt,
                                                    int* __restrict__ offs,
                                                    int Nn, int E)
{
    __shared__ int part[1024];
    const int t = threadIdx.x;
    const int CH = (Nn + 1023) / 1024;
    const int base = t * CH;
    int s = 0;
    for (int i = 0; i < CH; ++i) {
        int idx = base + i;
        if (idx < Nn) s += cnt[idx];
    }
    part[t] = s;
    __syncthreads();
    for (int d = 1; d < 1024; d <<= 1) {
        int v = (t >= d) ? part[t - d] : 0;
        __syncthreads();
        part[t] += v;
        __syncthreads();
    }
    int run = (t > 0) ? part[t - 1] : 0;
    for (int i = 0; i < CH; ++i) {
        int idx = base + i;
        if (idx < Nn) {
            offs[idx] = run;
            run += cnt[idx];
        }
    }
    if (t == 0) offs[Nn] = E;
}

__global__ __launch_bounds__(256) void scatter_perm(const int* __restrict__ dst,
                                                    const int* __restrict__ offs,
                                                    int* __restrict__ cur2,
                                                    int* __restrict__ perm, int E)
{
    int i = blockIdx.x * blockDim.x + threadIdx.x;
    const int stride = gridDim.x * blockDim.x;
    for (; i < E; i += stride) {
        int n = dst[i];
        int p = offs[n] + atomicAdd(&cur2[n], 1);
        perm[p] = i;
    }
}

// ---------------------------------------------------------------------------
// Fused edge phase: g = bf16(gelu((x[src]+ea) @ W1^T + b1)), natural order.
// One 64-edge tile per block. Staging is FULL-LINE COALESCED: chunk id
// gch = it*256+tid -> consecutive lanes read consecutive 16B chunks (ea:
// 1KB contiguous per instruction; x: two 512B row segments). f32->bf16 in
// registers, XOR-swizzled ds_write, swapped-operand MFMA, natural-order
// bf16 stores (no bases here; deferred to aggregate where it streams
// full rows).
// ---------------------------------------------------------------------------
__global__ __launch_bounds__(256) void fused_edge(
    const float* __restrict__ x, const float* __restrict__ ea,
    const int* __restrict__ src, const float* __restrict__ W1,
    const float* __restrict__ b1, unsigned short* __restrict__ gbuf, int E)
{
    __shared__ __align__(16) unsigned short alds[64 * 128];  // 16 KB

    const int tid = threadIdx.x;
    const int w = tid >> 6, l = tid & 63, lg = l >> 4, lr = l & 15;

    // W1 A-fragments: rows w*32 + ni*16 + lr, k = kk*32 + lg*8 .. +8
    bf16x8 wf[2][4];
    f32x4 b1v[2];
#pragma unroll
    for (int ni = 0; ni < 2; ++ni) {
        int row = w * 32 + ni * 16 + lr;
#pragma unroll
        for (int kk = 0; kk < 4; ++kk) {
            const float* p = W1 + row * H + kk * 32 + lg * 8;
            u16x8 tt;
#pragma unroll
            for (int i = 0; i < 8; ++i) tt[i] = f2bfu(p[i]);
            wf[ni][kk] = __builtin_bit_cast(bf16x8, tt);
        }
        b1v[ni] = *reinterpret_cast<const f32x4*>(b1 + w * 32 + ni * 16 + lg * 4);
    }

    const int e0 = blockIdx.x * 64;

    // ---- stage: 64 rows x 128 f32 -> bf16 LDS tile, coalesced ----
#pragma unroll
    for (int it = 0; it < 8; ++it) {
        const int gch = it * 256 + tid;      // 16B f32 chunk id, 0..2047
        const int row = gch >> 5;            // 0..63
        const int c16 = gch & 31;            // chunk within row
        const int er = e0 + row;
        const int ec = er < E ? er : E - 1;
        const int s = src[ec];
        f32x4 a = *reinterpret_cast<const f32x4*>(ea + (long)ec * H + c16 * 4);
        f32x4 b = *reinterpret_cast<const f32x4*>(x + (long)s * H + c16 * 4);
        u16x4 o;
#pragma unroll
        for (int j = 0; j < 4; ++j) o[j] = f2bfu(a[j] + b[j]);
        const int col = c16 * 4;
        const int scol = col ^ ((row & 7) << 3);
        *reinterpret_cast<u16x4*>(&alds[row * 128 + scol]) = o;
    }
    __syncthreads();

    // ---- compute + natural-order epilogue ----
#pragma unroll
    for (int s = 0; s < 4; ++s) {
        const int arow = s * 16 + lr;
        const int aswz = (arow & 7) << 3;
        bf16x8 af[4];
#pragma unroll
        for (int kk = 0; kk < 4; ++kk)
            af[kk] = __builtin_bit_cast(bf16x8,
                *reinterpret_cast<const u16x8*>(&alds[arow * 128 + ((kk * 32 + lg * 8) ^ aswz)]));
        const int es = e0 + s * 16 + lr;
#pragma unroll
        for (int ni = 0; ni < 2; ++ni) {
            f32x4 a4 = {0.f, 0.f, 0.f, 0.f};
#pragma unroll
            for (int kk = 0; kk < 4; ++kk)
                a4 = __builtin_amdgcn_mfma_f32_16x16x32_bf16(wf[ni][kk], af[kk], a4, 0, 0, 0);
            if (es < E) {
                u16x4 o;
#pragma unroll
                for (int r = 0; r < 4; ++r)
                    o[r] = f2bfu(gelu_exact(a4[r] + b1v[ni][r]));
                *reinterpret_cast<u16x4*>(gbuf + (size_t)es * H + w * 32 + ni * 16 + lg * 4) = o;
            }
        }
    }
}

// ---------------------------------------------------------------------------
// Phase B: aggr[n] = sum_{e in group(n)} g[e] * bases[e].
// One wave per node; per edge: g row (u32/lane) + bases row (f32x2/lane),
// both full-row coalesced; random row ORDER only. 4-row unroll.
// ---------------------------------------------------------------------------
__global__ __launch_bounds__(256) void aggregate_kernel(
    const unsigned short* __restrict__ gbuf, const float* __restrict__ bases,
    const int* __restrict__ perm, const int* __restrict__ offs,
    float* __restrict__ aggr, int Nn, int E)
{
    const int wv = threadIdx.x >> 6, lane = threadIdx.x & 63;
    const int n = blockIdx.x * 4 + wv;
    if (n >= Nn) return;
    const int lo = offs[n], hi = offs[n + 1];
    float a0 = 0.f, a1 = 0.f;
    int i = lo;
    for (; i + 3 < hi; i += 4) {
        int e0 = perm[i], e1 = perm[i + 1], e2 = perm[i + 2], e3 = perm[i + 3];
        e0 = (unsigned)e0 < (unsigned)E ? e0 : 0;
        e1 = (unsigned)e1 < (unsigned)E ? e1 : 0;
        e2 = (unsigned)e2 < (unsigned)E ? e2 : 0;
        e3 = (unsigned)e3 < (unsigned)E ? e3 : 0;
        unsigned u0 = *reinterpret_cast<const unsigned*>(gbuf + (size_t)e0 * H + lane * 2);
        unsigned u1 = *reinterpret_cast<const unsigned*>(gbuf + (size_t)e1 * H + lane * 2);
        unsigned u2 = *reinterpret_cast<const unsigned*>(gbuf + (size_t)e2 * H + lane * 2);
        unsigned u3 = *reinterpret_cast<const unsigned*>(gbuf + (size_t)e3 * H + lane * 2);
        f32x2 b0 = *reinterpret_cast<const f32x2*>(bases + (size_t)e0 * H + lane * 2);
        f32x2 b1_ = *reinterpret_cast<const f32x2*>(bases + (size_t)e1 * H + lane * 2);
        f32x2 b2 = *reinterpret_cast<const f32x2*>(bases + (size_t)e2 * H + lane * 2);
        f32x2 b3 = *reinterpret_cast<const f32x2*>(bases + (size_t)e3 * H + lane * 2);
        a0 += __builtin_bit_cast(float, u0 << 16) * b0[0]
            + __builtin_bit_cast(float, u1 << 16) * b1_[0]
            + __builtin_bit_cast(float, u2 << 16) * b2[0]
            + __builtin_bit_cast(float, u3 << 16) * b3[0];
        a1 += __builtin_bit_cast(float, u0 & 0xffff0000u) * b0[1]
            + __builtin_bit_cast(float, u1 & 0xffff0000u) * b1_[1]
            + __builtin_bit_cast(float, u2 & 0xffff0000u) * b2[1]
            + __builtin_bit_cast(float, u3 & 0xffff0000u) * b3[1];
    }
    for (; i < hi; ++i) {
        int e = perm[i];
        e = (unsigned)e < (unsigned)E ? e : 0;
        unsigned u0 = *reinterpret_cast<const unsigned*>(gbuf + (size_t)e * H + lane * 2);
        f32x2 b0 = *reinterpret_cast<const f32x2*>(bases + (size_t)e * H + lane * 2);
        a0 += __builtin_bit_cast(float, u0 << 16) * b0[0];
        a1 += __builtin_bit_cast(float, u0 & 0xffff0000u) * b0[1];
    }
    f32x2 o = {a0, a1};
    *reinterpret_cast<f32x2*>(aggr + (size_t)n * H + lane * 2) = o;
}

// ---------------------------------------------------------------------------
// Node GEMM  Y = f(A) @ W^T + bias, fused column sum/sumsq epilogue for BN
// stats. PRE=true applies gelu(a*scale+shift) on load.
// ---------------------------------------------------------------------------
template <bool PRE>
__global__ __launch_bounds__(256) void node_gemm(
    const float* __restrict__ A, const float* __restrict__ W,
    const float* __restrict__ bias, const float* __restrict__ scl,
    const float* __restrict__ shf, float* __restrict__ Y,
    float* __restrict__ csum, float* __restrict__ cssq, int Nn)
{
    __shared__ __align__(16) unsigned short alds[64 * 128];

    const int tid = threadIdx.x;
    const int w = tid >> 6, l = tid & 63, lg = l >> 4, lr = l & 15;
    const int er = tid >> 2, q = tid & 3;
    const int r0 = blockIdx.x * 64;

    bf16x8 bf[2][4];
    float bv[2];
#pragma unroll
    for (int n = 0; n < 2; ++n) {
        int row = w * 32 + n * 16 + lr;
        bv[n] = bias[row];
#pragma unroll
        for (int kk = 0; kk < 4; ++kk) {
            const float* p = W + row * H + kk * 32 + lg * 8;
            u16x8 t;
#pragma unroll
            for (int i = 0; i < 8; ++i) t[i] = f2bfu(p[i]);
            bf[n][kk] = __builtin_bit_cast(bf16x8, t);
        }
    }

    {
        int rr = r0 + er;
        int rc = rr < Nn ? rr : Nn - 1;
        const f32x4* pa = reinterpret_cast<const f32x4*>(A + (long)rc * H + q * 32);
        const int swz = (er & 7) << 3;
#pragma unroll
        for (int i = 0; i < 8; ++i) {
            f32x4 v = pa[i];
            if constexpr (PRE) {
                f32x4 sc = *reinterpret_cast<const f32x4*>(scl + q * 32 + i * 4);
                f32x4 sh = *reinterpret_cast<const f32x4*>(shf + q * 32 + i * 4);
#pragma unroll
                for (int c = 0; c < 4; ++c) v[c] = gelu_exact(v[c] * sc[c] + sh[c]);
            }
            u16x4 o;
            o[0] = f2bfu(v[0]);
            o[1] = f2bfu(v[1]);
            o[2] = f2bfu(v[2]);
            o[3] = f2bfu(v[3]);
            int col = q * 32 + i * 4;
            *reinterpret_cast<u16x4*>(&alds[er * 128 + (col ^ swz)]) = o;
        }
    }
    __syncthreads();

    float ps[2] = {0.f, 0.f}, ps2[2] = {0.f, 0.f};
#pragma unroll
    for (int m = 0; m < 4; ++m) {
        const int arow = m * 16 + lr;
        const int aswz = (arow & 7) << 3;
        bf16x8 af[4];
#pragma unroll
        for (int kk = 0; kk < 4; ++kk)
            af[kk] = __builtin_bit_cast(bf16x8,
                *reinterpret_cast<const u16x8*>(&alds[arow * 128 + ((kk * 32 + lg * 8) ^ aswz)]));
#pragma unroll
        for (int n = 0; n < 2; ++n) {
            f32x4 a4 = {0.f, 0.f, 0.f, 0.f};
#pragma unroll
            for (int kk = 0; kk < 4; ++kk)
                a4 = __builtin_amdgcn_mfma_f32_16x16x32_bf16(af[kk], bf[n][kk], a4, 0, 0, 0);
            const int j = w * 32 + n * 16 + lr;
#pragma unroll
            for (int r = 0; r < 4; ++r) {
                int rr = r0 + m * 16 + lg * 4 + r;
                if (rr < Nn) {
                    float z = a4[r] + bv[n];
                    Y[(long)rr * H + j] = z;
                    ps[n] += z;
                    ps2[n] += z * z;
                }
            }
        }
    }
#pragma unroll
    for (int n = 0; n < 2; ++n) {
        float s = ps[n];
        s += __shfl_xor(s, 16);
        s += __shfl_xor(s, 32);
        float s2 = ps2[n];
        s2 += __shfl_xor(s2, 16);
        s2 += __shfl_xor(s2, 32);
        if (lg == 0) {
            int j = w * 32 + n * 16 + lr;
            atomicAdd(&csum[j], s);
            atomicAdd(&cssq[j], s2);
        }
    }
}

__global__ void finalize_bn(const float* __restrict__ csum, const float* __restrict__ cssq,
                            const float* __restrict__ g, const float* __restrict__ be,
                            float* __restrict__ scl, float* __restrict__ shf, float invN)
{
    int j = threadIdx.x;
    float mu = csum[j] * invN;
    float var = fmaxf(cssq[j] * invN - mu * mu, 0.f);
    float s = g[j] * rsqrtf(var + EPS);
    scl[j] = s;
    shf[j] = be[j] - mu * s;
}

__global__ __launch_bounds__(256) void final_gelu(
    const float* __restrict__ Y2, const float* __restrict__ scl,
    const float* __restrict__ shf, float* __restrict__ out, long n4)
{
    long i = (long)blockIdx.x * blockDim.x + threadIdx.x;
    const long stride = (long)gridDim.x * blockDim.x;
    for (; i < n4; i += stride) {
        f32x4 v = reinterpret_cast<const f32x4*>(Y2)[i];
        int c4 = (int)(i & 31);
        f32x4 sc = reinterpret_cast<const f32x4*>(scl)[c4];
        f32x4 sh = reinterpret_cast<const f32x4*>(shf)[c4];
        f32x4 o;
#pragma unroll
        for (int c = 0; c < 4; ++c) o[c] = gelu_exact(v[c] * sc[c] + sh[c]);
        reinterpret_cast<f32x4*>(out)[i] = o;
    }
}

extern "C" void kernel_launch(void* const* d_in, const int* in_sizes, int n_in,
                              void* d_out, int out_size, void* d_ws, size_t ws_size,
                              hipStream_t stream) {
    const float* x     = (const float*)d_in[0];
    const float* ea    = (const float*)d_in[1];
    const float* bases = (const float*)d_in[2];
    const int*   src   = (const int*)d_in[3];
    const int*   dst   = (const int*)d_in[4];
    const float* W1    = (const float*)d_in[5];
    const float* b1    = (const float*)d_in[6];
    const float* W2    = (const float*)d_in[7];
    const float* b2    = (const float*)d_in[8];
    const float* g1    = (const float*)d_in[9];
    const float* be1   = (const float*)d_in[10];
    const float* W3    = (const float*)d_in[11];
    const float* b3    = (const float*)d_in[12];
    const float* g2    = (const float*)d_in[13];
    const float* be2   = (const float*)d_in[14];

    const int N = in_sizes[0] / H;
    const int E = in_sizes[1] / H;

    float* ws    = (float*)d_ws;
    float* aggr  = ws;                        // [N,H]; reused as y2
    float* y1    = aggr + (size_t)N * H;      // [N,H]
    float* stats = y1 + (size_t)N * H;        // 1024 floats
    float* sum1 = stats,        *ss1 = stats + 128;
    float* sum2 = stats + 256,  *ss2 = stats + 384;
    float* scl1 = stats + 512,  *shf1 = stats + 640;
    float* scl2 = stats + 768,  *shf2 = stats + 896;
    int* cnt  = (int*)(stats + 1024);         // [N] histogram
    int* cnt2 = cnt + N;                      // [N] scatter cursor (zeroed)
    int* perm = cnt2 + N;                     // [E]
    int* offs = perm + E;                     // [N+1]
    unsigned short* gbuf = (unsigned short*)(((uintptr_t)(offs + N + 1) + 4095) & ~(uintptr_t)4095); // [E,H] bf16

    // zero stats (1024 f32) + cnt (N) + cnt2 (N) with a kernel — the
    // in-graph hipMemsetAsync measured ~195 us for this 324 KB in R7.
    const int zn4 = (1024 + 2 * N + 3) / 4;
    zero_kernel<<<128, 256, 0, stream>>>((int*)stats, zn4);

    // --- counting sort (perm + offs) ---
    hist_kernel<<<2048, 256, 0, stream>>>(dst, cnt, E);
    scan_kernel<<<1, 1024, 0, stream>>>(cnt, offs, N, E);
    scatter_perm<<<2048, 256, 0, stream>>>(dst, offs, cnt2, perm, E);

    // --- Phase A: fused posE build + edge GEMM, natural-order g writes ---
    fused_edge<<<(E + 63) / 64, 256, 0, stream>>>(x, ea, src, W1, b1, gbuf, E);

    // --- Phase B: aggr = segment-sum(g * bases) via perm gather ---
    aggregate_kernel<<<(N + 3) / 4, 256, 0, stream>>>(gbuf, bases, perm, offs, aggr, N, E);

    // --- node pipeline ---
    const int nblk = (N + 63) / 64;
    node_gemm<false><<<nblk, 256, 0, stream>>>(aggr, W2, b2, nullptr, nullptr, y1, sum1, ss1, N);
    finalize_bn<<<1, 128, 0, stream>>>(sum1, ss1, g1, be1, scl1, shf1, 1.0f / (float)N);
    node_gemm<true><<<nblk, 256, 0, stream>>>(y1, W3, b3, scl1, shf1, aggr, sum2, ss2, N);
    finalize_bn<<<1, 128, 0, stream>>>(sum2, ss2, g2, be2, scl2, shf2, 1.0f / (float)N);

    long n4 = (long)N * H / 4;
    final_gelu<<<2048, 256, 0, stream>>>(aggr, scl2, shf2, (float*)d_out, n4);
}

// Round 9
// 471.285 us; speedup vs baseline: 1.3246x; 1.0170x over previous
//
#include <hip/hip_runtime.h>
#include <cmath>

#define H 128
#define EPS 1e-5f

typedef __attribute__((ext_vector_type(8))) __bf16 bf16x8;
typedef __attribute__((ext_vector_type(4))) float f32x4;
typedef __attribute__((ext_vector_type(2))) float f32x2;
typedef __attribute__((ext_vector_type(4))) unsigned short u16x4;
typedef __attribute__((ext_vector_type(8))) unsigned short u16x8;
typedef __attribute__((ext_vector_type(4))) int i32x4;

// Fast GELU: sigmoid form of the tanh approximation.
// gelu(x) ~= x * sigmoid(2t), t = 0.7978845608*(x + 0.044715 x^3)
//         =  x / (1 + exp(-2t))
// max abs err ~1e-3 vs exact erf GELU — below bf16 rounding of the result.
// Limits: x->+inf -> x; x->-inf -> -0. (exp overflow -> inf -> x/inf = 0.)
__device__ __forceinline__ float gelu_fast(float x) {
    float t2 = -1.5957691216057308f * fmaf(0.044715f * x * x, x, x); // -2t
    return x * __builtin_amdgcn_rcpf(1.0f + __expf(t2));
}

__device__ __forceinline__ unsigned short f2bfu(float f) {
    __bf16 h = (__bf16)f;   // RNE fptrunc
    return __builtin_bit_cast(unsigned short, h);
}

// ---------------------------------------------------------------------------
// Zero scratch (stats + cnt + cnt2) — replaces the pathologically slow
// in-graph hipMemsetAsync (measured 195 us for 324 KB in R7).
// ---------------------------------------------------------------------------
__global__ __launch_bounds__(256) void zero_kernel(int* __restrict__ p, int n4)
{
    int i = blockIdx.x * blockDim.x + threadIdx.x;
    const int stride = gridDim.x * blockDim.x;
    i32x4 z = {0, 0, 0, 0};
    for (; i < n4; i += stride)
        reinterpret_cast<i32x4*>(p)[i] = z;
}

// ---------------------------------------------------------------------------
// Counting sort of edges by dst -> perm (dst-grouped edge ids), offs.
// ---------------------------------------------------------------------------
__global__ __launch_bounds__(256) void hist_kernel(const int* __restrict__ dst,
                                                   int* __restrict__ cnt, int E)
{
    int i = blockIdx.x * blockDim.x + threadIdx.x;
    const int stride = gridDim.x * blockDim.x;
    for (; i < E; i += stride) atomicAdd(&cnt[dst[i]], 1);
}

__global__ __launch_bounds__(1024) void scan_kernel(const int* __restrict__ cnt,
                                                    int* __restrict__ offs,
                                                    int Nn, int E)
{
    __shared__ int part[1024];
    const int t = threadIdx.x;
    const int CH = (Nn + 1023) / 1024;
    const int base = t * CH;
    int s = 0;
    for (int i = 0; i < CH; ++i) {
        int idx = base + i;
        if (idx < Nn) s += cnt[idx];
    }
    part[t] = s;
    __syncthreads();
    for (int d = 1; d < 1024; d <<= 1) {
        int v = (t >= d) ? part[t - d] : 0;
        __syncthreads();
        part[t] += v;
        __syncthreads();
    }
    int run = (t > 0) ? part[t - 1] : 0;
    for (int i = 0; i < CH; ++i) {
        int idx = base + i;
        if (idx < Nn) {
            offs[idx] = run;
            run += cnt[idx];
        }
    }
    if (t == 0) offs[Nn] = E;
}

__global__ __launch_bounds__(256) void scatter_perm(const int* __restrict__ dst,
                                                    const int* __restrict__ offs,
                                                    int* __restrict__ cur2,
                                                    int* __restrict__ perm, int E)
{
    int i = blockIdx.x * blockDim.x + threadIdx.x;
    const int stride = gridDim.x * blockDim.x;
    for (; i < E; i += stride) {
        int n = dst[i];
        int p = offs[n] + atomicAdd(&cur2[n], 1);
        perm[p] = i;
    }
}

// ---------------------------------------------------------------------------
// Fused edge phase: g = bf16(gelu((x[src]+ea) @ W1^T + b1)), natural order.
// One 64-edge tile per block. Full-line-coalesced staging, XOR-swizzled
// ds_write, swapped-operand MFMA, fast-GELU epilogue, natural-order stores.
// ---------------------------------------------------------------------------
__global__ __launch_bounds__(256) void fused_edge(
    const float* __restrict__ x, const float* __restrict__ ea,
    const int* __restrict__ src, const float* __restrict__ W1,
    const float* __restrict__ b1, unsigned short* __restrict__ gbuf, int E)
{
    __shared__ __align__(16) unsigned short alds[64 * 128];  // 16 KB

    const int tid = threadIdx.x;
    const int w = tid >> 6, l = tid & 63, lg = l >> 4, lr = l & 15;

    // W1 A-fragments: rows w*32 + ni*16 + lr, k = kk*32 + lg*8 .. +8
    bf16x8 wf[2][4];
    f32x4 b1v[2];
#pragma unroll
    for (int ni = 0; ni < 2; ++ni) {
        int row = w * 32 + ni * 16 + lr;
#pragma unroll
        for (int kk = 0; kk < 4; ++kk) {
            const float* p = W1 + row * H + kk * 32 + lg * 8;
            u16x8 tt;
#pragma unroll
            for (int i = 0; i < 8; ++i) tt[i] = f2bfu(p[i]);
            wf[ni][kk] = __builtin_bit_cast(bf16x8, tt);
        }
        b1v[ni] = *reinterpret_cast<const f32x4*>(b1 + w * 32 + ni * 16 + lg * 4);
    }

    const int e0 = blockIdx.x * 64;

    // ---- stage: 64 rows x 128 f32 -> bf16 LDS tile, coalesced ----
#pragma unroll
    for (int it = 0; it < 8; ++it) {
        const int gch = it * 256 + tid;      // 16B f32 chunk id, 0..2047
        const int row = gch >> 5;            // 0..63
        const int c16 = gch & 31;            // chunk within row
        const int er = e0 + row;
        const int ec = er < E ? er : E - 1;
        const int s = src[ec];
        f32x4 a = *reinterpret_cast<const f32x4*>(ea + (long)ec * H + c16 * 4);
        f32x4 b = *reinterpret_cast<const f32x4*>(x + (long)s * H + c16 * 4);
        u16x4 o;
#pragma unroll
        for (int j = 0; j < 4; ++j) o[j] = f2bfu(a[j] + b[j]);
        const int col = c16 * 4;
        const int scol = col ^ ((row & 7) << 3);
        *reinterpret_cast<u16x4*>(&alds[row * 128 + scol]) = o;
    }
    __syncthreads();

    // ---- compute + natural-order epilogue ----
#pragma unroll
    for (int s = 0; s < 4; ++s) {
        const int arow = s * 16 + lr;
        const int aswz = (arow & 7) << 3;
        bf16x8 af[4];
#pragma unroll
        for (int kk = 0; kk < 4; ++kk)
            af[kk] = __builtin_bit_cast(bf16x8,
                *reinterpret_cast<const u16x8*>(&alds[arow * 128 + ((kk * 32 + lg * 8) ^ aswz)]));
        const int es = e0 + s * 16 + lr;
#pragma unroll
        for (int ni = 0; ni < 2; ++ni) {
            f32x4 a4 = {0.f, 0.f, 0.f, 0.f};
#pragma unroll
            for (int kk = 0; kk < 4; ++kk)
                a4 = __builtin_amdgcn_mfma_f32_16x16x32_bf16(wf[ni][kk], af[kk], a4, 0, 0, 0);
            if (es < E) {
                u16x4 o;
#pragma unroll
                for (int r = 0; r < 4; ++r)
                    o[r] = f2bfu(gelu_fast(a4[r] + b1v[ni][r]));
                *reinterpret_cast<u16x4*>(gbuf + (size_t)es * H + w * 32 + ni * 16 + lg * 4) = o;
            }
        }
    }
}

// ---------------------------------------------------------------------------
// Phase B: aggr[n] = sum_{e in group(n)} g[e] * bases[e].
// One wave per node; full-row coalesced reads; random row ORDER only.
// ---------------------------------------------------------------------------
__global__ __launch_bounds__(256) void aggregate_kernel(
    const unsigned short* __restrict__ gbuf, const float* __restrict__ bases,
    const int* __restrict__ perm, const int* __restrict__ offs,
    float* __restrict__ aggr, int Nn, int E)
{
    const int wv = threadIdx.x >> 6, lane = threadIdx.x & 63;
    const int n = blockIdx.x * 4 + wv;
    if (n >= Nn) return;
    const int lo = offs[n], hi = offs[n + 1];
    float a0 = 0.f, a1 = 0.f;
    int i = lo;
    for (; i + 3 < hi; i += 4) {
        int e0 = perm[i], e1 = perm[i + 1], e2 = perm[i + 2], e3 = perm[i + 3];
        e0 = (unsigned)e0 < (unsigned)E ? e0 : 0;
        e1 = (unsigned)e1 < (unsigned)E ? e1 : 0;
        e2 = (unsigned)e2 < (unsigned)E ? e2 : 0;
        e3 = (unsigned)e3 < (unsigned)E ? e3 : 0;
        unsigned u0 = *reinterpret_cast<const unsigned*>(gbuf + (size_t)e0 * H + lane * 2);
        unsigned u1 = *reinterpret_cast<const unsigned*>(gbuf + (size_t)e1 * H + lane * 2);
        unsigned u2 = *reinterpret_cast<const unsigned*>(gbuf + (size_t)e2 * H + lane * 2);
        unsigned u3 = *reinterpret_cast<const unsigned*>(gbuf + (size_t)e3 * H + lane * 2);
        f32x2 b0 = *reinterpret_cast<const f32x2*>(bases + (size_t)e0 * H + lane * 2);
        f32x2 b1_ = *reinterpret_cast<const f32x2*>(bases + (size_t)e1 * H + lane * 2);
        f32x2 b2 = *reinterpret_cast<const f32x2*>(bases + (size_t)e2 * H + lane * 2);
        f32x2 b3 = *reinterpret_cast<const f32x2*>(bases + (size_t)e3 * H + lane * 2);
        a0 += __builtin_bit_cast(float, u0 << 16) * b0[0]
            + __builtin_bit_cast(float, u1 << 16) * b1_[0]
            + __builtin_bit_cast(float, u2 << 16) * b2[0]
            + __builtin_bit_cast(float, u3 << 16) * b3[0];
        a1 += __builtin_bit_cast(float, u0 & 0xffff0000u) * b0[1]
            + __builtin_bit_cast(float, u1 & 0xffff0000u) * b1_[1]
            + __builtin_bit_cast(float, u2 & 0xffff0000u) * b2[1]
            + __builtin_bit_cast(float, u3 & 0xffff0000u) * b3[1];
    }
    for (; i < hi; ++i) {
        int e = perm[i];
        e = (unsigned)e < (unsigned)E ? e : 0;
        unsigned u0 = *reinterpret_cast<const unsigned*>(gbuf + (size_t)e * H + lane * 2);
        f32x2 b0 = *reinterpret_cast<const f32x2*>(bases + (size_t)e * H + lane * 2);
        a0 += __builtin_bit_cast(float, u0 << 16) * b0[0];
        a1 += __builtin_bit_cast(float, u0 & 0xffff0000u) * b0[1];
    }
    f32x2 o = {a0, a1};
    *reinterpret_cast<f32x2*>(aggr + (size_t)n * H + lane * 2) = o;
}

// ---------------------------------------------------------------------------
// Node GEMM  Y = f(A) @ W^T + bias, fused column sum/sumsq epilogue for BN
// stats. PRE=true applies gelu(a*scale+shift) on load.
// ---------------------------------------------------------------------------
template <bool PRE>
__global__ __launch_bounds__(256) void node_gemm(
    const float* __restrict__ A, const float* __restrict__ W,
    const float* __restrict__ bias, const float* __restrict__ scl,
    const float* __restrict__ shf, float* __restrict__ Y,
    float* __restrict__ csum, float* __restrict__ cssq, int Nn)
{
    __shared__ __align__(16) unsigned short alds[64 * 128];

    const int tid = threadIdx.x;
    const int w = tid >> 6, l = tid & 63, lg = l >> 4, lr = l & 15;
    const int er = tid >> 2, q = tid & 3;
    const int r0 = blockIdx.x * 64;

    bf16x8 bf[2][4];
    float bv[2];
#pragma unroll
    for (int n = 0; n < 2; ++n) {
        int row = w * 32 + n * 16 + lr;
        bv[n] = bias[row];
#pragma unroll
        for (int kk = 0; kk < 4; ++kk) {
            const float* p = W + row * H + kk * 32 + lg * 8;
            u16x8 t;
#pragma unroll
            for (int i = 0; i < 8; ++i) t[i] = f2bfu(p[i]);
            bf[n][kk] = __builtin_bit_cast(bf16x8, t);
        }
    }

    {
        int rr = r0 + er;
        int rc = rr < Nn ? rr : Nn - 1;
        const f32x4* pa = reinterpret_cast<const f32x4*>(A + (long)rc * H + q * 32);
        const int swz = (er & 7) << 3;
#pragma unroll
        for (int i = 0; i < 8; ++i) {
            f32x4 v = pa[i];
            if constexpr (PRE) {
                f32x4 sc = *reinterpret_cast<const f32x4*>(scl + q * 32 + i * 4);
                f32x4 sh = *reinterpret_cast<const f32x4*>(shf + q * 32 + i * 4);
#pragma unroll
                for (int c = 0; c < 4; ++c) v[c] = gelu_fast(v[c] * sc[c] + sh[c]);
            }
            u16x4 o;
            o[0] = f2bfu(v[0]);
            o[1] = f2bfu(v[1]);
            o[2] = f2bfu(v[2]);
            o[3] = f2bfu(v[3]);
            int col = q * 32 + i * 4;
            *reinterpret_cast<u16x4*>(&alds[er * 128 + (col ^ swz)]) = o;
        }
    }
    __syncthreads();

    float ps[2] = {0.f, 0.f}, ps2[2] = {0.f, 0.f};
#pragma unroll
    for (int m = 0; m < 4; ++m) {
        const int arow = m * 16 + lr;
        const int aswz = (arow & 7) << 3;
        bf16x8 af[4];
#pragma unroll
        for (int kk = 0; kk < 4; ++kk)
            af[kk] = __builtin_bit_cast(bf16x8,
                *reinterpret_cast<const u16x8*>(&alds[arow * 128 + ((kk * 32 + lg * 8) ^ aswz)]));
#pragma unroll
        for (int n = 0; n < 2; ++n) {
            f32x4 a4 = {0.f, 0.f, 0.f, 0.f};
#pragma unroll
            for (int kk = 0; kk < 4; ++kk)
                a4 = __builtin_amdgcn_mfma_f32_16x16x32_bf16(af[kk], bf[n][kk], a4, 0, 0, 0);
            const int j = w * 32 + n * 16 + lr;
#pragma unroll
            for (int r = 0; r < 4; ++r) {
                int rr = r0 + m * 16 + lg * 4 + r;
                if (rr < Nn) {
                    float z = a4[r] + bv[n];
                    Y[(long)rr * H + j] = z;
                    ps[n] += z;
                    ps2[n] += z * z;
                }
            }
        }
    }
#pragma unroll
    for (int n = 0; n < 2; ++n) {
        float s = ps[n];
        s += __shfl_xor(s, 16);
        s += __shfl_xor(s, 32);
        float s2 = ps2[n];
        s2 += __shfl_xor(s2, 16);
        s2 += __shfl_xor(s2, 32);
        if (lg == 0) {
            int j = w * 32 + n * 16 + lr;
            atomicAdd(&csum[j], s);
            atomicAdd(&cssq[j], s2);
        }
    }
}

__global__ void finalize_bn(const float* __restrict__ csum, const float* __restrict__ cssq,
                            const float* __restrict__ g, const float* __restrict__ be,
                            float* __restrict__ scl, float* __restrict__ shf, float invN)
{
    int j = threadIdx.x;
    float mu = csum[j] * invN;
    float var = fmaxf(cssq[j] * invN - mu * mu, 0.f);
    float s = g[j] * rsqrtf(var + EPS);
    scl[j] = s;
    shf[j] = be[j] - mu * s;
}

__global__ __launch_bounds__(256) void final_gelu(
    const float* __restrict__ Y2, const float* __restrict__ scl,
    const float* __restrict__ shf, float* __restrict__ out, long n4)
{
    long i = (long)blockIdx.x * blockDim.x + threadIdx.x;
    const long stride = (long)gridDim.x * blockDim.x;
    for (; i < n4; i += stride) {
        f32x4 v = reinterpret_cast<const f32x4*>(Y2)[i];
        int c4 = (int)(i & 31);
        f32x4 sc = reinterpret_cast<const f32x4*>(scl)[c4];
        f32x4 sh = reinterpret_cast<const f32x4*>(shf)[c4];
        f32x4 o;
#pragma unroll
        for (int c = 0; c < 4; ++c) o[c] = gelu_fast(v[c] * sc[c] + sh[c]);
        reinterpret_cast<f32x4*>(out)[i] = o;
    }
}

extern "C" void kernel_launch(void* const* d_in, const int* in_sizes, int n_in,
                              void* d_out, int out_size, void* d_ws, size_t ws_size,
                              hipStream_t stream) {
    const float* x     = (const float*)d_in[0];
    const float* ea    = (const float*)d_in[1];
    const float* bases = (const float*)d_in[2];
    const int*   src   = (const int*)d_in[3];
    const int*   dst   = (const int*)d_in[4];
    const float* W1    = (const float*)d_in[5];
    const float* b1    = (const float*)d_in[6];
    const float* W2    = (const float*)d_in[7];
    const float* b2    = (const float*)d_in[8];
    const float* g1    = (const float*)d_in[9];
    const float* be1   = (const float*)d_in[10];
    const float* W3    = (const float*)d_in[11];
    const float* b3    = (const float*)d_in[12];
    const float* g2    = (const float*)d_in[13];
    const float* be2   = (const float*)d_in[14];

    const int N = in_sizes[0] / H;
    const int E = in_sizes[1] / H;

    float* ws    = (float*)d_ws;
    float* aggr  = ws;                        // [N,H]; reused as y2
    float* y1    = aggr + (size_t)N * H;      // [N,H]
    float* stats = y1 + (size_t)N * H;        // 1024 floats
    float* sum1 = stats,        *ss1 = stats + 128;
    float* sum2 = stats + 256,  *ss2 = stats + 384;
    float* scl1 = stats + 512,  *shf1 = stats + 640;
    float* scl2 = stats + 768,  *shf2 = stats + 896;
    int* cnt  = (int*)(stats + 1024);         // [N] histogram
    int* cnt2 = cnt + N;                      // [N] scatter cursor (zeroed)
    int* perm = cnt2 + N;                     // [E]
    int* offs = perm + E;                     // [N+1]
    unsigned short* gbuf = (unsigned short*)(((uintptr_t)(offs + N + 1) + 4095) & ~(uintptr_t)4095); // [E,H] bf16

    // zero stats (1024 f32) + cnt (N) + cnt2 (N) with a kernel
    const int zn4 = (1024 + 2 * N + 3) / 4;
    zero_kernel<<<128, 256, 0, stream>>>((int*)stats, zn4);

    // --- counting sort (perm + offs) ---
    hist_kernel<<<2048, 256, 0, stream>>>(dst, cnt, E);
    scan_kernel<<<1, 1024, 0, stream>>>(cnt, offs, N, E);
    scatter_perm<<<2048, 256, 0, stream>>>(dst, offs, cnt2, perm, E);

    // --- Phase A: fused posE build + edge GEMM, natural-order g writes ---
    fused_edge<<<(E + 63) / 64, 256, 0, stream>>>(x, ea, src, W1, b1, gbuf, E);

    // --- Phase B: aggr = segment-sum(g * bases) via perm gather ---
    aggregate_kernel<<<(N + 3) / 4, 256, 0, stream>>>(gbuf, bases, perm, offs, aggr, N, E);

    // --- node pipeline ---
    const int nblk = (N + 63) / 64;
    node_gemm<false><<<nblk, 256, 0, stream>>>(aggr, W2, b2, nullptr, nullptr, y1, sum1, ss1, N);
    finalize_bn<<<1, 128, 0, stream>>>(sum1, ss1, g1, be1, scl1, shf1, 1.0f / (float)N);
    node_gemm<true><<<nblk, 256, 0, stream>>>(y1, W3, b3, scl1, shf1, aggr, sum2, ss2, N);
    finalize_bn<<<1, 128, 0, stream>>>(sum2, ss2, g2, be2, scl2, shf2, 1.0f / (float)N);

    long n4 = (long)N * H / 4;
    final_gelu<<<2048, 256, 0, stream>>>(aggr, scl2, shf2, (float*)d_out, n4);
}